// Round 7
// baseline (85.386 us; speedup 1.0000x reference)
//
#include <hip/hip_runtime.h>
#include <hip/hip_fp16.h>
#include <hip/hip_bf16.h>

#define NN 256
#define AA 1024
#define JJ 4096          // B*C
#define OUTW 1152        // A + B

typedef __attribute__((ext_vector_type(8))) short short8v;
typedef __attribute__((ext_vector_type(4))) float floatx4;

__device__ __forceinline__ unsigned f2bf(float f) {
    __hip_bfloat16 h = __float2bfloat16(f);   // RNE hardware convert
    return (unsigned)*(unsigned short*)&h;
}

// ---------------------------------------------------------------------------
// fused_all: ONE launch (the r2..r6 plateau at ~37us across three different
// kernel structures implicates inter-dispatch overhead, not kernel bodies).
// Grid 256 x 512 (1 block/CU -> all blocks co-resident; spin barrier safe).
//   phase 0: out[n][0:1024] = x   (block bid copies row bid)
//   phase A: M = x @ T   (r4-verified 64x64 bf16-MFMA tile, double-buffered
//            LDS, 1 barrier/chunk; M stored f16 to d_ws)
//   grid barrier: threadfence(release,wbL2) + atomicAdd + spin +
//            threadfence(acquire,invL1/L2); counter pre-zeroed via
//            hipMemsetAsync each call -> deterministic, capture-safe.
//   phase B: o[n][b] = sum_m exp(-L1(M_n,M_m))  (r6 pairwise body)
// LDS swizzle everywhere: byte ^= ((row&7)<<4) on write AND read (rule 21).
// ---------------------------------------------------------------------------
__global__ __launch_bounds__(512) void fused_all(const float* __restrict__ x,
                                                 const float* __restrict__ T,
                                                 float* __restrict__ out,
                                                 __half* __restrict__ Mh,
                                                 unsigned* __restrict__ cnt) {
    __shared__ __align__(16) char arena[32768];
    unsigned short* xs0 = (unsigned short*)arena;            // 8 KB
    unsigned short* xs1 = (unsigned short*)(arena + 8192);   // 8 KB
    unsigned short* ts0 = (unsigned short*)(arena + 16384);  // 8 KB
    unsigned short* ts1 = (unsigned short*)(arena + 24576);  // 8 KB

    const int bid = blockIdx.x;
    const int tid = threadIdx.x;
    const int lane = tid & 63;
    const int w = tid >> 6;

    // ---- phase 0: copy x row 'bid' into out ----
    if (tid < 256) {
        *(float4*)&out[(size_t)bid * OUTW + tid * 4] =
            *(const float4*)&x[(size_t)bid * AA + tid * 4];
    }

    // ---- phase A: gemm, tile 64n x 64j, TK=64, 16 chunks ----
    const int col0 = (bid & 63) * 64;
    const int row0 = (bid >> 6) * 64;

    // staging assignments
    const int ar = tid >> 3;                  // A row 0..63
    const int ak = (tid & 7) * 8;             // A k elem offset
    const int bj = (tid & 31) * 2;            // B col pair 0..62
    const int bk = (tid >> 5) * 4;            // B k elem offset 0..60

    // compute assignments
    const int g = lane >> 4;
    const int rf = lane & 15;
    const int arow = (w & 3) * 16 + rf;       // fragment A row
    const int bcol = (w >> 2) * 32 + rf;      // fragment B col (first tile)

    floatx4 acc0 = {0.f, 0.f, 0.f, 0.f};
    floatx4 acc1 = {0.f, 0.f, 0.f, 0.f};

    const float* xrow = &x[(size_t)(row0 + ar) * AA + ak];
    const float* tcol = &T[(size_t)bk * JJ + col0 + bj];

    const int aWr = ar * 128 + ((ak * 2) ^ ((ar & 7) << 4));
    const int bWr0 = bj * 128 + ((bk * 2) ^ ((bj & 7) << 4));
    const int bWr1 = (bj + 1) * 128 + ((bk * 2) ^ (((bj + 1) & 7) << 4));
    const int swzA = (arow & 7) << 4;
    const int swzB = (bcol & 7) << 4;         // (bcol+16)&7 == bcol&7
    const int aRd0 = arow * 128 + ((g * 16) ^ swzA);
    const int aRd1 = arow * 128 + ((64 + g * 16) ^ swzA);
    const int bB0 = bcol * 128;
    const int bB1 = (bcol + 16) * 128;
    const int kOffB0 = (g * 16) ^ swzB;
    const int kOffB1 = (64 + g * 16) ^ swzB;

    // prologue: prefetch chunk 0
    float4 va = *(const float4*)(xrow);
    float4 vb = *(const float4*)(xrow + 4);
    float2 q0 = *(const float2*)(tcol);
    float2 q1 = *(const float2*)(tcol + JJ);
    float2 q2 = *(const float2*)(tcol + 2 * JJ);
    float2 q3 = *(const float2*)(tcol + 3 * JJ);

    for (int c = 0; c < 16; ++c) {
        unsigned short* xsb = (c & 1) ? xs1 : xs0;
        unsigned short* tsb = (c & 1) ? ts1 : ts0;
        // stage chunk c (regs from last iteration's prefetch)
        uint4 pa;
        pa.x = f2bf(va.x) | (f2bf(va.y) << 16);
        pa.y = f2bf(va.z) | (f2bf(va.w) << 16);
        pa.z = f2bf(vb.x) | (f2bf(vb.y) << 16);
        pa.w = f2bf(vb.z) | (f2bf(vb.w) << 16);
        *(uint4*)((char*)xsb + aWr) = pa;
        uint2 p0, p1;
        p0.x = f2bf(q0.x) | (f2bf(q1.x) << 16);
        p0.y = f2bf(q2.x) | (f2bf(q3.x) << 16);
        p1.x = f2bf(q0.y) | (f2bf(q1.y) << 16);
        p1.y = f2bf(q2.y) | (f2bf(q3.y) << 16);
        *(uint2*)((char*)tsb + bWr0) = p0;
        *(uint2*)((char*)tsb + bWr1) = p1;
        // issue prefetch for chunk c+1
        if (c < 15) {
            const float* xq = xrow + (c + 1) * 64;
            va = *(const float4*)(xq);
            vb = *(const float4*)(xq + 4);
            const float* tq = tcol + (size_t)(c + 1) * 64 * JJ;
            q0 = *(const float2*)(tq);
            q1 = *(const float2*)(tq + JJ);
            q2 = *(const float2*)(tq + 2 * JJ);
            q3 = *(const float2*)(tq + 3 * JJ);
        }
        __syncthreads();
        // compute chunk c. Race-free: stage(c+2) into this buffer happens
        // after barrier(c+1), which is after these reads.
        short8v a0 = *(const short8v*)((char*)xsb + aRd0);
        short8v b00 = *(const short8v*)((char*)tsb + bB0 + kOffB0);
        short8v b10 = *(const short8v*)((char*)tsb + bB1 + kOffB0);
        acc0 = __builtin_amdgcn_mfma_f32_16x16x32_bf16(a0, b00, acc0, 0, 0, 0);
        acc1 = __builtin_amdgcn_mfma_f32_16x16x32_bf16(a0, b10, acc1, 0, 0, 0);
        short8v a1 = *(const short8v*)((char*)xsb + aRd1);
        short8v b01 = *(const short8v*)((char*)tsb + bB0 + kOffB1);
        short8v b11 = *(const short8v*)((char*)tsb + bB1 + kOffB1);
        acc0 = __builtin_amdgcn_mfma_f32_16x16x32_bf16(a1, b01, acc0, 0, 0, 0);
        acc1 = __builtin_amdgcn_mfma_f32_16x16x32_bf16(a1, b11, acc1, 0, 0, 0);
    }

    // epilogue A: C/D layout col = lane&15, row = (lane>>4)*4 + reg
    const int colw = col0 + (w >> 2) * 32 + rf;
    const int rbase = row0 + (w & 3) * 16 + (lane >> 4) * 4;
#pragma unroll
    for (int r = 0; r < 4; ++r) {
        Mh[(size_t)(rbase + r) * JJ + colw] = __float2half(acc0[r]);
        Mh[(size_t)(rbase + r) * JJ + colw + 16] = __float2half(acc1[r]);
    }

    // ---- grid barrier (device scope; cnt pre-zeroed by host memsetAsync) ----
    __syncthreads();                      // all block stores issued & drained
    if (tid == 0) {
        __threadfence();                  // release: write back L2 (agent scope)
        atomicAdd(cnt, 1u);
        while (__hip_atomic_load(cnt, __ATOMIC_RELAXED,
                                 __HIP_MEMORY_SCOPE_AGENT) < 256u) {
            __builtin_amdgcn_s_sleep(2);
        }
    }
    __syncthreads();
    __threadfence();                      // acquire: invalidate L1/L2

    // ---- phase B: pairwise (r6 body), LDS arena reused ----
    __half (*Mb)[32] = (__half(*)[32])arena;              // 16 KB
    float (*red)[128] = (float(*)[128])(arena + 16384);   // 4 KB
    const int b = bid & 127;
    const int h = bid >> 7;

    {   // stage all 256 rows of M[:, b, :]
        const int m = tid >> 1;
        const int ch = (tid & 1) * 16;
        *(uint4*)&Mb[m][ch] = *(const uint4*)&Mh[(size_t)m * JJ + b * 32 + ch];
        *(uint4*)&Mb[m][ch + 8] =
            *(const uint4*)&Mh[(size_t)m * JJ + b * 32 + ch + 8];
    }

    const int np = (tid & 63) * 2;        // n-pair within half
    const int mq = tid >> 6;              // 0..7 (uniform per wave)
    const int n0 = h * 128 + np;

    union u4h { uint4 u; __half2 hh[4]; };
    u4h mv[2][4];
#pragma unroll
    for (int r = 0; r < 2; ++r)
#pragma unroll
        for (int i = 0; i < 4; ++i)
            mv[r][i].u = *(const uint4*)&Mh[(size_t)(n0 + r) * JJ + b * 32 + i * 8];

    __syncthreads();

    float o0 = 0.f, o1 = 0.f;
    const int m0 = mq * 32;
    for (int m = m0; m < m0 + 32; ++m) {
        u4h rv[4];
#pragma unroll
        for (int i = 0; i < 4; ++i) rv[i].u = *(const uint4*)&Mb[m][i * 8];
#pragma unroll
        for (int r = 0; r < 2; ++r) {
            __half2 a0 = __habs2(__hsub2(mv[r][0].hh[0], rv[0].hh[0]));
            __half2 a1 = __habs2(__hsub2(mv[r][0].hh[1], rv[0].hh[1]));
            __half2 a2 = __habs2(__hsub2(mv[r][0].hh[2], rv[0].hh[2]));
            __half2 a3 = __habs2(__hsub2(mv[r][0].hh[3], rv[0].hh[3]));
#pragma unroll
            for (int i = 1; i < 4; ++i) {
                a0 = __hadd2(a0, __habs2(__hsub2(mv[r][i].hh[0], rv[i].hh[0])));
                a1 = __hadd2(a1, __habs2(__hsub2(mv[r][i].hh[1], rv[i].hh[1])));
                a2 = __hadd2(a2, __habs2(__hsub2(mv[r][i].hh[2], rv[i].hh[2])));
                a3 = __hadd2(a3, __habs2(__hsub2(mv[r][i].hh[3], rv[i].hh[3])));
            }
            __half2 s = __hadd2(__hadd2(a0, a1), __hadd2(a2, a3));
            float2 lf = __half22float2(s);
            float e = __expf(-(lf.x + lf.y));
            if (r == 0) o0 += e; else o1 += e;
        }
    }

    *(float2*)&red[mq][np] = make_float2(o0, o1);
    __syncthreads();
    if (tid < 128) {
        float o = 0.f;
#pragma unroll
        for (int qq = 0; qq < 8; ++qq) o += red[qq][tid];
        out[(size_t)(h * 128 + tid) * OUTW + AA + b] = o;
    }
}

// ===========================================================================
extern "C" void kernel_launch(void* const* d_in, const int* in_sizes, int n_in,
                              void* d_out, int out_size, void* d_ws, size_t ws_size,
                              hipStream_t stream) {
    const float* x = (const float*)d_in[0];
    const float* T = (const float*)d_in[1];
    float* out = (float*)d_out;
    __half* Mh = (__half*)d_ws;                               // 2 MB
    unsigned* cnt = (unsigned*)((char*)d_ws + (size_t)NN * JJ * 2);

    hipMemsetAsync(cnt, 0, sizeof(unsigned), stream);         // capture-safe
    fused_all<<<256, 512, 0, stream>>>(x, T, out, Mh, cnt);
}

// Round 8
// 34.786 us; speedup vs baseline: 2.4546x; 2.4546x over previous
//
#include <hip/hip_runtime.h>
#include <hip/hip_fp16.h>
#include <hip/hip_bf16.h>

#define NN 256
#define AA 1024
#define JJ 4096          // B*C
#define OUTW 1152        // A + B

typedef __attribute__((ext_vector_type(8))) short short8v;
typedef __attribute__((ext_vector_type(4))) float floatx4;

__device__ __forceinline__ unsigned f2bf(float f) {
    __hip_bfloat16 h = __float2bfloat16(f);   // RNE hardware convert
    return (unsigned)*(unsigned short*)&h;
}

// ---------------------------------------------------------------------------
// gemm: M[n][j] = sum_k x[n][k]*T[k][j]; f32 in, bf16 MFMA 16x16x32, f16 out.
// r6-verified structure; change: prefetch distance 2 (loop unrolled x2 with
// STATIC register sets A/B — rule 20), so chunk c+2's global loads are issued
// at chunk c and stay in flight ~2 chunk-times (~600 cyc) instead of ~250:
// covers the HBM latency of T (L3 is evicted by the harness's 262MB poison
// fills between replays, so T comes from HBM every replay).
// Tile 32n x 64j, TK=64. Grid (64 j, 8 n) = 512 blocks (2/CU), 256 thr.
// LDS [row][64k] bf16, XOR swizzle byte^=((row&7)<<4) write AND read (rule 21).
// One barrier per chunk; race-freedom: compute(c) ds-reads complete (lgkmcnt
// waited before MFMA issue) before barrier(c+1); stage(c+2) is after it.
// ---------------------------------------------------------------------------
__global__ __launch_bounds__(256) void gemm(const float* __restrict__ x,
                                            const float* __restrict__ T,
                                            __half* __restrict__ Mh) {
    __shared__ unsigned short xs[2][32 * 64];   // 4 KB each
    __shared__ unsigned short ts[2][64 * 64];   // 8 KB each

    const int tid = threadIdx.x;
    const int lane = tid & 63;
    const int w = tid >> 6;
    const int col0 = blockIdx.x * 64;
    const int row0 = blockIdx.y * 32;

    // A staging: 1 row x 8 k per thread
    const int xr = tid >> 3;
    const int xk = (tid & 7) * 8;
    const float* xp = x + (size_t)(row0 + xr) * AA + xk;
    const int xW = xr * 128 + ((xk * 2) ^ ((xr & 7) << 4));

    // B staging: 4 j x 4 k per thread (transpose + convert)
    const int tj = (tid & 15) * 4;
    const int tk = (tid >> 4) * 4;
    const float* tp = T + (size_t)tk * JJ + col0 + tj;
    int tWr[4];
#pragma unroll
    for (int q = 0; q < 4; ++q) {
        const int row = tj + q;
        tWr[q] = row * 128 + ((tk * 2) ^ ((row & 7) << 4));
    }

    // compute assignments
    const int rf = lane & 15;
    const int g = lane >> 4;
    const int nh = w & 1;
    const int jh = w >> 1;
    const int swz = (rf & 7) << 4;
    const int aBase = (nh * 16 + rf) * 128;
    const int b0Base = (jh * 32 + rf) * 128;
    const int b1Base = (jh * 32 + 16 + rf) * 128;
    const int k0off = (g * 16) ^ swz;
    const int k1off = (64 + g * 16) ^ swz;

    floatx4 acc0 = {0.f, 0.f, 0.f, 0.f};
    floatx4 acc1 = {0.f, 0.f, 0.f, 0.f};

    // prologue: prefetch chunk 0 -> set A, chunk 1 -> set B
    float4 xaA = *(const float4*)(xp);
    float4 xbA = *(const float4*)(xp + 4);
    float4 t0A = *(const float4*)(tp);
    float4 t1A = *(const float4*)(tp + JJ);
    float4 t2A = *(const float4*)(tp + 2 * JJ);
    float4 t3A = *(const float4*)(tp + 3 * JJ);
    float4 xaB = *(const float4*)(xp + 64);
    float4 xbB = *(const float4*)(xp + 68);
    const float* tpB = tp + (size_t)64 * JJ;
    float4 t0B = *(const float4*)(tpB);
    float4 t1B = *(const float4*)(tpB + JJ);
    float4 t2B = *(const float4*)(tpB + 2 * JJ);
    float4 t3B = *(const float4*)(tpB + 3 * JJ);

#pragma unroll 1
    for (int c = 0; c < 16; c += 2) {
        // ---------- even step: chunk c from set A, buf 0 ----------
        {
            uint4 pa;
            pa.x = f2bf(xaA.x) | (f2bf(xaA.y) << 16);
            pa.y = f2bf(xaA.z) | (f2bf(xaA.w) << 16);
            pa.z = f2bf(xbA.x) | (f2bf(xbA.y) << 16);
            pa.w = f2bf(xbA.z) | (f2bf(xbA.w) << 16);
            *(uint4*)((char*)xs[0] + xW) = pa;
            uint2 p;
            p.x = f2bf(t0A.x) | (f2bf(t1A.x) << 16);
            p.y = f2bf(t2A.x) | (f2bf(t3A.x) << 16);
            *(uint2*)((char*)ts[0] + tWr[0]) = p;
            p.x = f2bf(t0A.y) | (f2bf(t1A.y) << 16);
            p.y = f2bf(t2A.y) | (f2bf(t3A.y) << 16);
            *(uint2*)((char*)ts[0] + tWr[1]) = p;
            p.x = f2bf(t0A.z) | (f2bf(t1A.z) << 16);
            p.y = f2bf(t2A.z) | (f2bf(t3A.z) << 16);
            *(uint2*)((char*)ts[0] + tWr[2]) = p;
            p.x = f2bf(t0A.w) | (f2bf(t1A.w) << 16);
            p.y = f2bf(t2A.w) | (f2bf(t3A.w) << 16);
            *(uint2*)((char*)ts[0] + tWr[3]) = p;
        }
        if (c + 2 < 16) {   // reload set A with chunk c+2
            const float* xq = xp + (c + 2) * 64;
            xaA = *(const float4*)(xq);
            xbA = *(const float4*)(xq + 4);
            const float* tq = tp + (size_t)(c + 2) * 64 * JJ;
            t0A = *(const float4*)(tq);
            t1A = *(const float4*)(tq + JJ);
            t2A = *(const float4*)(tq + 2 * JJ);
            t3A = *(const float4*)(tq + 3 * JJ);
        }
        __syncthreads();
        {
            short8v a0 = *(const short8v*)((char*)xs[0] + aBase + k0off);
            short8v b00 = *(const short8v*)((char*)ts[0] + b0Base + k0off);
            short8v b10 = *(const short8v*)((char*)ts[0] + b1Base + k0off);
            acc0 = __builtin_amdgcn_mfma_f32_16x16x32_bf16(a0, b00, acc0, 0, 0, 0);
            acc1 = __builtin_amdgcn_mfma_f32_16x16x32_bf16(a0, b10, acc1, 0, 0, 0);
            short8v a1 = *(const short8v*)((char*)xs[0] + aBase + k1off);
            short8v b01 = *(const short8v*)((char*)ts[0] + b0Base + k1off);
            short8v b11 = *(const short8v*)((char*)ts[0] + b1Base + k1off);
            acc0 = __builtin_amdgcn_mfma_f32_16x16x32_bf16(a1, b01, acc0, 0, 0, 0);
            acc1 = __builtin_amdgcn_mfma_f32_16x16x32_bf16(a1, b11, acc1, 0, 0, 0);
        }
        // ---------- odd step: chunk c+1 from set B, buf 1 ----------
        {
            uint4 pa;
            pa.x = f2bf(xaB.x) | (f2bf(xaB.y) << 16);
            pa.y = f2bf(xaB.z) | (f2bf(xaB.w) << 16);
            pa.z = f2bf(xbB.x) | (f2bf(xbB.y) << 16);
            pa.w = f2bf(xbB.z) | (f2bf(xbB.w) << 16);
            *(uint4*)((char*)xs[1] + xW) = pa;
            uint2 p;
            p.x = f2bf(t0B.x) | (f2bf(t1B.x) << 16);
            p.y = f2bf(t2B.x) | (f2bf(t3B.x) << 16);
            *(uint2*)((char*)ts[1] + tWr[0]) = p;
            p.x = f2bf(t0B.y) | (f2bf(t1B.y) << 16);
            p.y = f2bf(t2B.y) | (f2bf(t3B.y) << 16);
            *(uint2*)((char*)ts[1] + tWr[1]) = p;
            p.x = f2bf(t0B.z) | (f2bf(t1B.z) << 16);
            p.y = f2bf(t2B.z) | (f2bf(t3B.z) << 16);
            *(uint2*)((char*)ts[1] + tWr[2]) = p;
            p.x = f2bf(t0B.w) | (f2bf(t1B.w) << 16);
            p.y = f2bf(t2B.w) | (f2bf(t3B.w) << 16);
            *(uint2*)((char*)ts[1] + tWr[3]) = p;
        }
        if (c + 3 < 16) {   // reload set B with chunk c+3
            const float* xq = xp + (c + 3) * 64;
            xaB = *(const float4*)(xq);
            xbB = *(const float4*)(xq + 4);
            const float* tq = tp + (size_t)(c + 3) * 64 * JJ;
            t0B = *(const float4*)(tq);
            t1B = *(const float4*)(tq + JJ);
            t2B = *(const float4*)(tq + 2 * JJ);
            t3B = *(const float4*)(tq + 3 * JJ);
        }
        __syncthreads();
        {
            short8v a0 = *(const short8v*)((char*)xs[1] + aBase + k0off);
            short8v b00 = *(const short8v*)((char*)ts[1] + b0Base + k0off);
            short8v b10 = *(const short8v*)((char*)ts[1] + b1Base + k0off);
            acc0 = __builtin_amdgcn_mfma_f32_16x16x32_bf16(a0, b00, acc0, 0, 0, 0);
            acc1 = __builtin_amdgcn_mfma_f32_16x16x32_bf16(a0, b10, acc1, 0, 0, 0);
            short8v a1 = *(const short8v*)((char*)xs[1] + aBase + k1off);
            short8v b01 = *(const short8v*)((char*)ts[1] + b0Base + k1off);
            short8v b11 = *(const short8v*)((char*)ts[1] + b1Base + k1off);
            acc0 = __builtin_amdgcn_mfma_f32_16x16x32_bf16(a1, b01, acc0, 0, 0, 0);
            acc1 = __builtin_amdgcn_mfma_f32_16x16x32_bf16(a1, b11, acc1, 0, 0, 0);
        }
    }

    // C/D layout: col = lane&15, row = (lane>>4)*4 + reg
    const int colw = col0 + jh * 32 + rf;
    const int rbase = row0 + nh * 16 + g * 4;
#pragma unroll
    for (int r = 0; r < 4; ++r) {
        Mh[(size_t)(rbase + r) * JJ + colw] = __float2half(acc0[r]);
        Mh[(size_t)(rbase + r) * JJ + colw + 16] = __float2half(acc1[r]);
    }
}

// ---------------------------------------------------------------------------
// pairwise: o[n][b] = sum_m exp(-sum_c |M[n][b,c]-M[m][b,c]|), f16 packed.
// Regrid for occupancy: 512 blocks = (b = bid&127, quarter q = bid>>7),
// 512 thr = 32 n-pairs x 16 m-groups -> 2 blocks/CU, 16 waves/CU (the r2..r7
// plateau was latency at 8 waves/CU). Thread: 2 n x 16 m. Per-wave rv reads
// span <=2 m values (tid>>5 differs by 1 across the wave) -> 2-way broadcast,
// free (m136). x-copy folded in (blocks bid<128) -> one launch fewer.
// ---------------------------------------------------------------------------
__global__ __launch_bounds__(512) void pairwise(const __half* __restrict__ Mh,
                                                const float* __restrict__ x,
                                                float* __restrict__ out) {
    __shared__ __half Mb[256][32];    // 16 KB
    __shared__ float red[16][64];     // 4 KB
    const int bid = blockIdx.x;
    const int b = bid & 127;
    const int q = bid >> 7;           // n-quarter 0..3
    const int tid = threadIdx.x;

    // folded x-copy: blocks 0..127 copy out[:,0:1024] = x (2 rows each)
    if (bid < 128) {
        const int row = bid * 2 + (tid >> 8);
        const int c4 = (tid & 255) * 4;
        *(float4*)&out[(size_t)row * OUTW + c4] =
            *(const float4*)&x[(size_t)row * AA + c4];
    }

    {   // stage all 256 rows of M[:, b, :]
        const int m = tid >> 1;
        const int ch = (tid & 1) * 16;
        *(uint4*)&Mb[m][ch] = *(const uint4*)&Mh[(size_t)m * JJ + b * 32 + ch];
        *(uint4*)&Mb[m][ch + 8] =
            *(const uint4*)&Mh[(size_t)m * JJ + b * 32 + ch + 8];
    }

    const int np = (tid & 31) * 2;    // n-pair within quarter (0..62)
    const int mg = tid >> 5;          // m-group 0..15
    const int n0 = q * 64 + np;

    union u4h { uint4 u; __half2 hh[4]; };
    u4h mv[2][4];
#pragma unroll
    for (int r = 0; r < 2; ++r)
#pragma unroll
        for (int i = 0; i < 4; ++i)
            mv[r][i].u = *(const uint4*)&Mh[(size_t)(n0 + r) * JJ + b * 32 + i * 8];

    __syncthreads();

    float o0 = 0.f, o1 = 0.f;
    const int m0 = mg * 16;
    for (int m = m0; m < m0 + 16; ++m) {
        u4h rv[4];
#pragma unroll
        for (int i = 0; i < 4; ++i) rv[i].u = *(const uint4*)&Mb[m][i * 8];
#pragma unroll
        for (int r = 0; r < 2; ++r) {
            __half2 a0 = __habs2(__hsub2(mv[r][0].hh[0], rv[0].hh[0]));
            __half2 a1 = __habs2(__hsub2(mv[r][0].hh[1], rv[0].hh[1]));
            __half2 a2 = __habs2(__hsub2(mv[r][0].hh[2], rv[0].hh[2]));
            __half2 a3 = __habs2(__hsub2(mv[r][0].hh[3], rv[0].hh[3]));
#pragma unroll
            for (int i = 1; i < 4; ++i) {
                a0 = __hadd2(a0, __habs2(__hsub2(mv[r][i].hh[0], rv[i].hh[0])));
                a1 = __hadd2(a1, __habs2(__hsub2(mv[r][i].hh[1], rv[i].hh[1])));
                a2 = __hadd2(a2, __habs2(__hsub2(mv[r][i].hh[2], rv[i].hh[2])));
                a3 = __hadd2(a3, __habs2(__hsub2(mv[r][i].hh[3], rv[i].hh[3])));
            }
            __half2 s = __hadd2(__hadd2(a0, a1), __hadd2(a2, a3));
            float2 lf = __half22float2(s);
            float e = __expf(-(lf.x + lf.y));
            if (r == 0) o0 += e; else o1 += e;
        }
    }

    *(float2*)&red[mg][np] = make_float2(o0, o1);
    __syncthreads();
    if (tid < 64) {
        float o = 0.f;
#pragma unroll
        for (int g2 = 0; g2 < 16; ++g2) o += red[g2][tid];
        out[(size_t)(q * 64 + tid) * OUTW + AA + b] = o;
    }
}

// ===========================================================================
extern "C" void kernel_launch(void* const* d_in, const int* in_sizes, int n_in,
                              void* d_out, int out_size, void* d_ws, size_t ws_size,
                              hipStream_t stream) {
    const float* x = (const float*)d_in[0];
    const float* T = (const float*)d_in[1];
    float* out = (float*)d_out;
    __half* Mh = (__half*)d_ws;               // 2 MB

    gemm<<<dim3(64, 8), 256, 0, stream>>>(x, T, Mh);
    pairwise<<<512, 512, 0, stream>>>(Mh, x, out);
}